// Round 17
// baseline (630.919 us; speedup 1.0000x reference)
//
#include <hip/hip_runtime.h>
#include <hip/hip_bf16.h>

typedef __attribute__((ext_vector_type(4))) float f32x4;
typedef __attribute__((ext_vector_type(8))) short s16x8;

#define NTOK 65536
// K layout (1056 = 33 chunks of 32): 16 pairs [32 Wb-k | 32 We-k], then tail
// chunk 32: [8 LoRA-B rows | bb | be | 22 zero].

__device__ __forceinline__ unsigned short f2b(float f) {
    __hip_bfloat16 h = __float2bfloat16(f);
    return *reinterpret_cast<unsigned short*>(&h);
}

// ---------------- P1: fused router (blocks 0..1023) + prep (1024..5247) -----
// 512 threads: router = 8 waves x 8 tokens (halved serial depth vs R15).
__global__ __launch_bounds__(512) void prep_router_kernel(
    const float* __restrict__ x, const float* __restrict__ A,
    const float* __restrict__ Wr, const float* __restrict__ br,
    const float* __restrict__ Wb, const float* __restrict__ bb,
    const float* __restrict__ B, const float* __restrict__ ia3,
    const float* __restrict__ We, const float* __restrict__ be,
    unsigned short* __restrict__ Wfrag,
    float* __restrict__ wgt, float* __restrict__ tws,
    int* __restrict__ perm, int* __restrict__ cnt)
{
    const int tid = threadIdx.x;
    if (blockIdx.x >= 1024) {
        // ---------------- prep: Wfrag[e][c][cb][lane][8] MFMA-frag order ----
        int i = (blockIdx.x - 1024) * 512 + tid;    // 4*33*32*512 = 2162688
        if (i >= 4 * 33 * 32 * 512) return;
        const int j    = i & 7;
        const int lane = (i >> 3) & 63;
        const int cb   = (i >> 9) & 31;
        const int rest = i >> 14;                   // e*33 + c
        const int c    = rest % 33;
        const int e    = rest / 33;
        const int col  = cb * 16 + (lane & 15);
        const int klin = c * 32 + ((lane >> 4) << 3) + j;
        float v;
        if (klin < 1024) {
            const int p = klin >> 6, q = klin & 63;
            if (q < 32) v = Wb[col * 512 + p * 32 + q] * ia3[col];
            else        v = We[((size_t)e * 512 + col) * 512 + p * 32 + (q - 32)];
        }
        else if (klin < 1032)  v = B[(klin - 1024) * 512 + col] * 4.0f * ia3[col];
        else if (klin == 1032) v = bb[col] * ia3[col];
        else if (klin == 1033) v = be[e * 512 + col];
        else                   v = 0.0f;
        Wfrag[i] = f2b(v);
        return;
    }

    // ---------------- router: 8 waves x 8 tokens --------------------------
    __shared__ int sCnt[4];
    __shared__ int sBase[4];
    __shared__ int sE[64];
    __shared__ int sPos[64];

    const int wave = tid >> 6, lane = tid & 63;
    const int k0 = lane * 8;

    f32x4 wrv[4][2];
#pragma unroll
    for (int e = 0; e < 4; ++e) {
        wrv[e][0] = *(const f32x4*)(Wr + e * 512 + k0);
        wrv[e][1] = *(const f32x4*)(Wr + e * 512 + k0 + 4);
    }
    f32x4 av[8][2];
#pragma unroll
    for (int j = 0; j < 8; ++j) {
        av[j][0] = *(const f32x4*)(A + (size_t)(k0 + j) * 8);
        av[j][1] = *(const f32x4*)(A + (size_t)(k0 + j) * 8 + 4);
    }
    const float br0 = br[0], br1 = br[1], br2 = br[2], br3 = br[3];

    if (tid < 4) sCnt[tid] = 0;
    __syncthreads();

    const int tok0 = blockIdx.x * 64 + wave * 8;
    f32x4 x0 = *(const f32x4*)(x + (size_t)tok0 * 512 + k0);
    f32x4 x1 = *(const f32x4*)(x + (size_t)tok0 * 512 + k0 + 4);
    for (int it = 0; it < 8; ++it) {
        const int tok = tok0 + it;
        f32x4 n0, n1;
        if (it < 7) {
            const float* nr = x + (size_t)(tok + 1) * 512 + k0;
            n0 = *(const f32x4*)nr;
            n1 = *(const f32x4*)(nr + 4);
        }
        float ar[4] = {0.f, 0.f, 0.f, 0.f};
        float at[8] = {0.f, 0.f, 0.f, 0.f, 0.f, 0.f, 0.f, 0.f};
#pragma unroll
        for (int j = 0; j < 8; ++j) {
            const float xv = (j < 4) ? x0[j] : x1[j - 4];
#pragma unroll
            for (int e = 0; e < 4; ++e) ar[e] += xv * wrv[e][j >> 2][j & 3];
#pragma unroll
            for (int r = 0; r < 8; ++r) at[r] += xv * av[j][r >> 2][r & 3];
        }
#pragma unroll
        for (int off = 32; off >= 1; off >>= 1) {
#pragma unroll
            for (int e = 0; e < 4; ++e) ar[e] += __shfl_xor(ar[e], off);
#pragma unroll
            for (int r = 0; r < 8; ++r) at[r] += __shfl_xor(at[r], off);
        }
        if (lane == 0) {
            const float l0 = ar[0] + br0, l1 = ar[1] + br1;
            const float l2 = ar[2] + br2, l3 = ar[3] + br3;
            int e = 0; float m = l0;
            if (l1 > m) { m = l1; e = 1; }
            if (l2 > m) { m = l2; e = 2; }
            if (l3 > m) { m = l3; e = 3; }
            const float s = expf(l0 - m) + expf(l1 - m) + expf(l2 - m) + expf(l3 - m);
            wgt[tok] = 1.0f / s;  // top value is exp(0)=1
            float* tp = tws + (size_t)tok * 8;
#pragma unroll
            for (int r = 0; r < 8; ++r) tp[r] = at[r];
            const int slot = wave * 8 + it;
            sE[slot] = e;
            sPos[slot] = atomicAdd(&sCnt[e], 1);
        }
        x0 = n0; x1 = n1;
    }
    __syncthreads();
    if (tid < 4) sBase[tid] = atomicAdd(&cnt[tid], sCnt[tid]);
    __syncthreads();
    if (tid < 64) {
        const int e = sE[tid];
        perm[e * NTOK + sBase[e] + sPos[tid]] = blockIdx.x * 64 + tid;
    }
}

// ---------------- P3: 64x256 tile, B global->reg (fragment-coalesced) -------
// R15 structure verbatim (empirical optimum): 4 waves, wave-tile 64x64, B
// triple-buffered in regs via Wfrag coalesced dwordx4, zero B-path barriers;
// A: 4 x 8 KB LDS ring staged two pairs ahead, barrier every other pair.
__global__ __launch_bounds__(256, 4) void main_kernel(
    const float* __restrict__ x, const unsigned short* __restrict__ Wfrag,
    const float* __restrict__ wgt, const float* __restrict__ tws,
    const int* __restrict__ perm, const int* __restrict__ cnt,
    float* __restrict__ out)
{
    __shared__ unsigned short sA[4][64 * 64];    // 4 x 8 KB ring, pair p -> p&3

    const int bid = blockIdx.x;
    const int xcd = bid & 7;
    const int e = xcd >> 1;
    const int par = xcd & 1;
    const int r = bid >> 3;
    const int half = r & 1;
    const int mt = (r >> 1) * 2 + par;
    const int n = cnt[e];
    const int base = mt * 64;
    if (base >= n) return;
    const int mcount = min(64, n - base);

    const int tid = threadIdx.x;
    const int lane = tid & 63;
    const int wave = tid >> 6;      // 0..3: owns cols half*256 + wave*64 ..+63
    const int lanelo = lane & 15;
    const int g = lane >> 4;        // 0..3

    // ---- A staging: thread -> (arow = tid>>2, s = tid&3); 8 f32 per pair ---
    const int arow = tid >> 2;
    const int s = tid & 3;
    const int atok = perm[e * NTOK + base + min(arow, mcount - 1)];
    const float* axp = x + (size_t)atok * 512 + s * 8;
    const float* atp = tws + (size_t)atok * 8;
    const float aw = wgt[atok];
    const int arx = arow & 7;
    const int adP = arow * 128 + ((s ^ arx) << 4);        // plain granule
    const int adS = arow * 128 + (((4 + s) ^ arx) << 4);  // w-scaled granule

    // ---- B: 4 fragment base pointers, each loads at +lane*16 (coalesced) ---
    const unsigned short* wB[4];
#pragma unroll
    for (int nb = 0; nb < 4; ++nb) {
        const int cb = half * 16 + wave * 4 + nb;          // colblk 0..31
        wB[nb] = Wfrag + (((size_t)e * 33 * 32) + cb) * 512 + lane * 8;
    }

    // triple-buffered B fragments; all indices compile-time after full unroll
    s16x8 bB[3][4];
    auto loadB = [&](int c, int ring) {
        const size_t co = (size_t)c * 32 * 512;            // chunk stride (elems)
#pragma unroll
        for (int nb = 0; nb < 4; ++nb)
            bB[ring][nb] = *(const s16x8*)(wB[nb] + co);
    };

    f32x4 qa, qb;   // A staging regs (named)
    auto loadA = [&](int p) {
        if (p < 16) {
            qa = *(const f32x4*)(axp + p * 32);
            qb = *(const f32x4*)(axp + p * 32 + 4);
        } else {
            qa = *(const f32x4*)atp;
            qb = *(const f32x4*)(atp + 4);
        }
    };
    auto writeA = [&](int p) {
        char* aB = (char*)sA[p & 3];
        s16x8 h0, h1;
        if (p < 16) {
#pragma unroll
            for (int j4 = 0; j4 < 4; ++j4) {
                h0[j4]     = (short)f2b(qa[j4]);
                h0[j4 + 4] = (short)f2b(qb[j4]);
                h1[j4]     = (short)f2b(aw * qa[j4]);
                h1[j4 + 4] = (short)f2b(aw * qb[j4]);
            }
        } else {
#pragma unroll
            for (int j4 = 0; j4 < 8; ++j4) { h0[j4] = 0; h1[j4] = 0; }
            if (s == 0) {
#pragma unroll
                for (int j4 = 0; j4 < 4; ++j4) {
                    h0[j4]     = (short)f2b(qa[j4]);
                    h0[j4 + 4] = (short)f2b(qb[j4]);
                }
            } else if (s == 1) {
                h0[0] = (short)f2b(1.0f);
                h0[1] = (short)f2b(aw);
            }
        }
        *(s16x8*)(aB + adP) = h0;
        *(s16x8*)(aB + adS) = h1;
    };

    f32x4 acc[4][4];
#pragma unroll
    for (int mb = 0; mb < 4; ++mb)
#pragma unroll
        for (int nb = 0; nb < 4; ++nb) acc[mb][nb] = (f32x4){0.f, 0.f, 0.f, 0.f};

    auto computeC = [&](int h, int abuf, int ring) {
        const char* bA = (const char*)sA[abuf];
        s16x8 a[4];
#pragma unroll
        for (int mb = 0; mb < 4; ++mb) {
            const int row = mb * 16 + lanelo;
            a[mb] = *(const s16x8*)(bA + row * 128 + ((((h << 2) + g) ^ (row & 7)) << 4));
        }
        __builtin_amdgcn_s_setprio(1);
#pragma unroll
        for (int mb = 0; mb < 4; ++mb)
#pragma unroll
            for (int nb = 0; nb < 4; ++nb)
                acc[mb][nb] = __builtin_amdgcn_mfma_f32_16x16x32_bf16(a[mb], bB[ring][nb], acc[mb][nb], 0, 0, 0);
        __builtin_amdgcn_s_setprio(0);
    };

    // ---- prologue: A before B in FIFO; B(0..2) in flight (chunk c -> c%3) --
    loadA(0);
    loadB(0, 0);
    loadB(1, 1);
    loadB(2, 2);
    writeA(0);                    // compiler vmcnt retires only the A load
    loadA(1);
    writeA(1);
    asm volatile("s_waitcnt lgkmcnt(0)" ::: "memory");
    __builtin_amdgcn_sched_barrier(0);
    __builtin_amdgcn_s_barrier();
    __builtin_amdgcn_sched_barrier(0);

    // pair p lives in sA[p&3]; written 2 iters ahead; barrier after odd iters.
    // chunk c lives in bB[c%3]; refilled with chunk c+3 right after use.
#pragma unroll
    for (int j = 0; j < 16; ++j) {
        if (j < 15) loadA(j + 2);          // prefetch pair j+2 (global)
        computeC(0, j & 3, (2 * j) % 3);   // chunk 2j (auto-wait on its regs)
        if (2 * j + 3 <= 32) loadB(2 * j + 3, (2 * j) % 3);
        computeC(1, j & 3, (2 * j + 1) % 3);
        if (2 * j + 4 <= 32) loadB(2 * j + 4, (2 * j + 1) % 3);
        if (j < 15) writeA(j + 2);         // ring slot (j+2)&3: race-free
        if (j & 1) {
            asm volatile("s_waitcnt lgkmcnt(0)" ::: "memory");
            __builtin_amdgcn_sched_barrier(0);
            __builtin_amdgcn_s_barrier();  // one barrier per TWO pairs
            __builtin_amdgcn_sched_barrier(0);
        }
    }

    // ---- tail pair 16 (chunk 32: LoRA + biases + w); 32%3 == 2 ----
    computeC(0, 0, 2);

    // ---- epilogue: bare scattered store ----
    const int col0 = half * 256 + wave * 64 + lanelo;
#pragma unroll
    for (int mb = 0; mb < 4; ++mb) {
#pragma unroll
        for (int rr = 0; rr < 4; ++rr) {
            const int trow = mb * 16 + g * 4 + rr;
            if (trow < mcount) {
                const int tok = perm[e * NTOK + base + trow];
                float* orow = out + (size_t)tok * 512 + col0;
                orow[0]  = acc[mb][0][rr];
                orow[16] = acc[mb][1][rr];
                orow[32] = acc[mb][2][rr];
                orow[48] = acc[mb][3][rr];
            }
        }
    }
}

extern "C" void kernel_launch(void* const* d_in, const int* in_sizes, int n_in,
                              void* d_out, int out_size, void* d_ws, size_t ws_size,
                              hipStream_t stream)
{
    const float* x   = (const float*)d_in[0];
    const float* Wb  = (const float*)d_in[1];
    const float* bb  = (const float*)d_in[2];
    const float* A   = (const float*)d_in[3];
    const float* B   = (const float*)d_in[4];
    const float* ia3 = (const float*)d_in[5];
    const float* Wr  = (const float*)d_in[6];
    const float* br  = (const float*)d_in[7];
    const float* We  = (const float*)d_in[8];
    const float* be  = (const float*)d_in[9];
    float* out = (float*)d_out;

    char* w = (char*)d_ws;
    int* cnt              = (int*)w;                      // 256 B
    unsigned short* Wfrag = (unsigned short*)(w + 256);   // 4*33*32*512*2 = 4325376
    float* wgt            = (float*)(w + 4325632);        // 65536*4
    float* tws            = (float*)(w + 4587776);        // 65536*8*4
    int* perm             = (int*)(w + 6684928);          // 4*65536*4 -> end 7733504

    hipMemsetAsync(cnt, 0, 16, stream);   // zero expert counters (graph-legal)
    // blocks 0..1023 = router (8 waves x 8 tokens); 1024..5247 = prep (512 thr)
    hipLaunchKernelGGL(prep_router_kernel, dim3(5248), dim3(512), 0, stream,
                       x, A, Wr, br, Wb, bb, B, ia3, We, be,
                       Wfrag, wgt, tws, perm, cnt);
    // 8 xcd x 144 slots x 2 halves
    hipLaunchKernelGGL(main_kernel, dim3(2304), dim3(256), 0, stream,
                       x, Wfrag, wgt, tws, perm, cnt, out);
}

// Round 18
// 185.428 us; speedup vs baseline: 3.4025x; 3.4025x over previous
//
#include <hip/hip_runtime.h>
#include <hip/hip_bf16.h>

typedef __attribute__((ext_vector_type(4))) float f32x4;
typedef __attribute__((ext_vector_type(8))) short s16x8;

#define NTOK 65536
// K layout (1056 = 33 chunks of 32): 16 pairs [32 Wb-k | 32 We-k], then tail
// chunk 32: [8 LoRA-B rows | bb | be | 22 zero].

__device__ __forceinline__ unsigned short f2b(float f) {
    __hip_bfloat16 h = __float2bfloat16(f);
    return *reinterpret_cast<unsigned short*>(&h);
}

// ---------------- P1: fused router (blocks 0..1023) + prep (1024..5247) -----
// 512 threads: router = 8 waves x 8 tokens.
__global__ __launch_bounds__(512) void prep_router_kernel(
    const float* __restrict__ x, const float* __restrict__ A,
    const float* __restrict__ Wr, const float* __restrict__ br,
    const float* __restrict__ Wb, const float* __restrict__ bb,
    const float* __restrict__ B, const float* __restrict__ ia3,
    const float* __restrict__ We, const float* __restrict__ be,
    unsigned short* __restrict__ Wfrag,
    float* __restrict__ wgt, float* __restrict__ tws,
    int* __restrict__ perm, int* __restrict__ cnt)
{
    const int tid = threadIdx.x;
    if (blockIdx.x >= 1024) {
        // ---------------- prep: Wfrag[e][c][cb][lane][8] MFMA-frag order ----
        int i = (blockIdx.x - 1024) * 512 + tid;    // 4*33*32*512 = 2162688
        if (i >= 4 * 33 * 32 * 512) return;
        const int j    = i & 7;
        const int lane = (i >> 3) & 63;
        const int cb   = (i >> 9) & 31;
        const int rest = i >> 14;                   // e*33 + c
        const int c    = rest % 33;
        const int e    = rest / 33;
        const int col  = cb * 16 + (lane & 15);
        const int klin = c * 32 + ((lane >> 4) << 3) + j;
        float v;
        if (klin < 1024) {
            const int p = klin >> 6, q = klin & 63;
            if (q < 32) v = Wb[col * 512 + p * 32 + q] * ia3[col];
            else        v = We[((size_t)e * 512 + col) * 512 + p * 32 + (q - 32)];
        }
        else if (klin < 1032)  v = B[(klin - 1024) * 512 + col] * 4.0f * ia3[col];
        else if (klin == 1032) v = bb[col] * ia3[col];
        else if (klin == 1033) v = be[e * 512 + col];
        else                   v = 0.0f;
        Wfrag[i] = f2b(v);
        return;
    }

    // ---------------- router: 8 waves x 8 tokens --------------------------
    __shared__ int sCnt[4];
    __shared__ int sBase[4];
    __shared__ int sE[64];
    __shared__ int sPos[64];

    const int wave = tid >> 6, lane = tid & 63;
    const int k0 = lane * 8;

    f32x4 wrv[4][2];
#pragma unroll
    for (int e = 0; e < 4; ++e) {
        wrv[e][0] = *(const f32x4*)(Wr + e * 512 + k0);
        wrv[e][1] = *(const f32x4*)(Wr + e * 512 + k0 + 4);
    }
    f32x4 av[8][2];
#pragma unroll
    for (int j = 0; j < 8; ++j) {
        av[j][0] = *(const f32x4*)(A + (size_t)(k0 + j) * 8);
        av[j][1] = *(const f32x4*)(A + (size_t)(k0 + j) * 8 + 4);
    }
    const float br0 = br[0], br1 = br[1], br2 = br[2], br3 = br[3];

    if (tid < 4) sCnt[tid] = 0;
    __syncthreads();

    const int tok0 = blockIdx.x * 64 + wave * 8;
    f32x4 x0 = *(const f32x4*)(x + (size_t)tok0 * 512 + k0);
    f32x4 x1 = *(const f32x4*)(x + (size_t)tok0 * 512 + k0 + 4);
    for (int it = 0; it < 8; ++it) {
        const int tok = tok0 + it;
        f32x4 n0, n1;
        if (it < 7) {
            const float* nr = x + (size_t)(tok + 1) * 512 + k0;
            n0 = *(const f32x4*)nr;
            n1 = *(const f32x4*)(nr + 4);
        }
        float ar[4] = {0.f, 0.f, 0.f, 0.f};
        float at[8] = {0.f, 0.f, 0.f, 0.f, 0.f, 0.f, 0.f, 0.f};
#pragma unroll
        for (int j = 0; j < 8; ++j) {
            const float xv = (j < 4) ? x0[j] : x1[j - 4];
#pragma unroll
            for (int e = 0; e < 4; ++e) ar[e] += xv * wrv[e][j >> 2][j & 3];
#pragma unroll
            for (int r = 0; r < 8; ++r) at[r] += xv * av[j][r >> 2][r & 3];
        }
#pragma unroll
        for (int off = 32; off >= 1; off >>= 1) {
#pragma unroll
            for (int e = 0; e < 4; ++e) ar[e] += __shfl_xor(ar[e], off);
#pragma unroll
            for (int r = 0; r < 8; ++r) at[r] += __shfl_xor(at[r], off);
        }
        if (lane == 0) {
            const float l0 = ar[0] + br0, l1 = ar[1] + br1;
            const float l2 = ar[2] + br2, l3 = ar[3] + br3;
            int e = 0; float m = l0;
            if (l1 > m) { m = l1; e = 1; }
            if (l2 > m) { m = l2; e = 2; }
            if (l3 > m) { m = l3; e = 3; }
            const float s = expf(l0 - m) + expf(l1 - m) + expf(l2 - m) + expf(l3 - m);
            wgt[tok] = 1.0f / s;  // top value is exp(0)=1
            float* tp = tws + (size_t)tok * 8;
#pragma unroll
            for (int r = 0; r < 8; ++r) tp[r] = at[r];
            const int slot = wave * 8 + it;
            sE[slot] = e;
            sPos[slot] = atomicAdd(&sCnt[e], 1);
        }
        x0 = n0; x1 = n1;
    }
    __syncthreads();
    if (tid < 4) sBase[tid] = atomicAdd(&cnt[tid], sCnt[tid]);
    __syncthreads();
    if (tid < 64) {
        const int e = sE[tid];
        perm[e * NTOK + sBase[e] + sPos[tid]] = blockIdx.x * 64 + tid;
    }
}

// ---------------- P3: 64x256 tile, B global->reg (fragment-coalesced) -------
// R15 structure verbatim (empirical optimum): 4 waves, wave-tile 64x64, B
// triple-buffered in regs via Wfrag coalesced dwordx4, zero B-path barriers;
// A: 4 x 8 KB LDS ring staged two pairs ahead, barrier every other pair.
// launch_bounds(256,3): 84 VGPR, NO SPILL (4 forces 64-reg cap -> scratch
// catastrophe, R17: FETCH 88->760 MB, main 94->540 us).
__global__ __launch_bounds__(256, 3) void main_kernel(
    const float* __restrict__ x, const unsigned short* __restrict__ Wfrag,
    const float* __restrict__ wgt, const float* __restrict__ tws,
    const int* __restrict__ perm, const int* __restrict__ cnt,
    float* __restrict__ out)
{
    __shared__ unsigned short sA[4][64 * 64];    // 4 x 8 KB ring, pair p -> p&3

    const int bid = blockIdx.x;
    const int xcd = bid & 7;
    const int e = xcd >> 1;
    const int par = xcd & 1;
    const int r = bid >> 3;
    const int half = r & 1;
    const int mt = (r >> 1) * 2 + par;
    const int n = cnt[e];
    const int base = mt * 64;
    if (base >= n) return;
    const int mcount = min(64, n - base);

    const int tid = threadIdx.x;
    const int lane = tid & 63;
    const int wave = tid >> 6;      // 0..3: owns cols half*256 + wave*64 ..+63
    const int lanelo = lane & 15;
    const int g = lane >> 4;        // 0..3

    // ---- A staging: thread -> (arow = tid>>2, s = tid&3); 8 f32 per pair ---
    const int arow = tid >> 2;
    const int s = tid & 3;
    const int atok = perm[e * NTOK + base + min(arow, mcount - 1)];
    const float* axp = x + (size_t)atok * 512 + s * 8;
    const float* atp = tws + (size_t)atok * 8;
    const float aw = wgt[atok];
    const int arx = arow & 7;
    const int adP = arow * 128 + ((s ^ arx) << 4);        // plain granule
    const int adS = arow * 128 + (((4 + s) ^ arx) << 4);  // w-scaled granule

    // ---- B: 4 fragment base pointers, each loads at +lane*16 (coalesced) ---
    const unsigned short* wB[4];
#pragma unroll
    for (int nb = 0; nb < 4; ++nb) {
        const int cb = half * 16 + wave * 4 + nb;          // colblk 0..31
        wB[nb] = Wfrag + (((size_t)e * 33 * 32) + cb) * 512 + lane * 8;
    }

    // triple-buffered B fragments; all indices compile-time after full unroll
    s16x8 bB[3][4];
    auto loadB = [&](int c, int ring) {
        const size_t co = (size_t)c * 32 * 512;            // chunk stride (elems)
#pragma unroll
        for (int nb = 0; nb < 4; ++nb)
            bB[ring][nb] = *(const s16x8*)(wB[nb] + co);
    };

    f32x4 qa, qb;   // A staging regs (named)
    auto loadA = [&](int p) {
        if (p < 16) {
            qa = *(const f32x4*)(axp + p * 32);
            qb = *(const f32x4*)(axp + p * 32 + 4);
        } else {
            qa = *(const f32x4*)atp;
            qb = *(const f32x4*)(atp + 4);
        }
    };
    auto writeA = [&](int p) {
        char* aB = (char*)sA[p & 3];
        s16x8 h0, h1;
        if (p < 16) {
#pragma unroll
            for (int j4 = 0; j4 < 4; ++j4) {
                h0[j4]     = (short)f2b(qa[j4]);
                h0[j4 + 4] = (short)f2b(qb[j4]);
                h1[j4]     = (short)f2b(aw * qa[j4]);
                h1[j4 + 4] = (short)f2b(aw * qb[j4]);
            }
        } else {
#pragma unroll
            for (int j4 = 0; j4 < 8; ++j4) { h0[j4] = 0; h1[j4] = 0; }
            if (s == 0) {
#pragma unroll
                for (int j4 = 0; j4 < 4; ++j4) {
                    h0[j4]     = (short)f2b(qa[j4]);
                    h0[j4 + 4] = (short)f2b(qb[j4]);
                }
            } else if (s == 1) {
                h0[0] = (short)f2b(1.0f);
                h0[1] = (short)f2b(aw);
            }
        }
        *(s16x8*)(aB + adP) = h0;
        *(s16x8*)(aB + adS) = h1;
    };

    f32x4 acc[4][4];
#pragma unroll
    for (int mb = 0; mb < 4; ++mb)
#pragma unroll
        for (int nb = 0; nb < 4; ++nb) acc[mb][nb] = (f32x4){0.f, 0.f, 0.f, 0.f};

    auto computeC = [&](int h, int abuf, int ring) {
        const char* bA = (const char*)sA[abuf];
        s16x8 a[4];
#pragma unroll
        for (int mb = 0; mb < 4; ++mb) {
            const int row = mb * 16 + lanelo;
            a[mb] = *(const s16x8*)(bA + row * 128 + ((((h << 2) + g) ^ (row & 7)) << 4));
        }
        __builtin_amdgcn_s_setprio(1);
#pragma unroll
        for (int mb = 0; mb < 4; ++mb)
#pragma unroll
            for (int nb = 0; nb < 4; ++nb)
                acc[mb][nb] = __builtin_amdgcn_mfma_f32_16x16x32_bf16(a[mb], bB[ring][nb], acc[mb][nb], 0, 0, 0);
        __builtin_amdgcn_s_setprio(0);
    };

    // ---- prologue: A before B in FIFO; B(0..2) in flight (chunk c -> c%3) --
    loadA(0);
    loadB(0, 0);
    loadB(1, 1);
    loadB(2, 2);
    writeA(0);                    // compiler vmcnt retires only the A load
    loadA(1);
    writeA(1);
    asm volatile("s_waitcnt lgkmcnt(0)" ::: "memory");
    __builtin_amdgcn_sched_barrier(0);
    __builtin_amdgcn_s_barrier();
    __builtin_amdgcn_sched_barrier(0);

    // pair p lives in sA[p&3]; written 2 iters ahead; barrier after odd iters.
    // chunk c lives in bB[c%3]; refilled with chunk c+3 right after use.
#pragma unroll
    for (int j = 0; j < 16; ++j) {
        if (j < 15) loadA(j + 2);          // prefetch pair j+2 (global)
        computeC(0, j & 3, (2 * j) % 3);   // chunk 2j (auto-wait on its regs)
        if (2 * j + 3 <= 32) loadB(2 * j + 3, (2 * j) % 3);
        computeC(1, j & 3, (2 * j + 1) % 3);
        if (2 * j + 4 <= 32) loadB(2 * j + 4, (2 * j + 1) % 3);
        if (j < 15) writeA(j + 2);         // ring slot (j+2)&3: race-free
        if (j & 1) {
            asm volatile("s_waitcnt lgkmcnt(0)" ::: "memory");
            __builtin_amdgcn_sched_barrier(0);
            __builtin_amdgcn_s_barrier();  // one barrier per TWO pairs
            __builtin_amdgcn_sched_barrier(0);
        }
    }

    // ---- tail pair 16 (chunk 32: LoRA + biases + w); 32%3 == 2 ----
    computeC(0, 0, 2);

    // ---- epilogue: bare scattered store ----
    const int col0 = half * 256 + wave * 64 + lanelo;
#pragma unroll
    for (int mb = 0; mb < 4; ++mb) {
#pragma unroll
        for (int rr = 0; rr < 4; ++rr) {
            const int trow = mb * 16 + g * 4 + rr;
            if (trow < mcount) {
                const int tok = perm[e * NTOK + base + trow];
                float* orow = out + (size_t)tok * 512 + col0;
                orow[0]  = acc[mb][0][rr];
                orow[16] = acc[mb][1][rr];
                orow[32] = acc[mb][2][rr];
                orow[48] = acc[mb][3][rr];
            }
        }
    }
}

extern "C" void kernel_launch(void* const* d_in, const int* in_sizes, int n_in,
                              void* d_out, int out_size, void* d_ws, size_t ws_size,
                              hipStream_t stream)
{
    const float* x   = (const float*)d_in[0];
    const float* Wb  = (const float*)d_in[1];
    const float* bb  = (const float*)d_in[2];
    const float* A   = (const float*)d_in[3];
    const float* B   = (const float*)d_in[4];
    const float* ia3 = (const float*)d_in[5];
    const float* Wr  = (const float*)d_in[6];
    const float* br  = (const float*)d_in[7];
    const float* We  = (const float*)d_in[8];
    const float* be  = (const float*)d_in[9];
    float* out = (float*)d_out;

    char* w = (char*)d_ws;
    int* cnt              = (int*)w;                      // 256 B
    unsigned short* Wfrag = (unsigned short*)(w + 256);   // 4*33*32*512*2 = 4325376
    float* wgt            = (float*)(w + 4325632);        // 65536*4
    float* tws            = (float*)(w + 4587776);        // 65536*8*4
    int* perm             = (int*)(w + 6684928);          // 4*65536*4 -> end 7733504

    hipMemsetAsync(cnt, 0, 16, stream);   // zero expert counters (graph-legal)
    // blocks 0..1023 = router (8 waves x 8 tokens); 1024..5247 = prep (512 thr)
    hipLaunchKernelGGL(prep_router_kernel, dim3(5248), dim3(512), 0, stream,
                       x, A, Wr, br, Wb, bb, B, ia3, We, be,
                       Wfrag, wgt, tws, perm, cnt);
    // 8 xcd x 144 slots x 2 halves
    hipLaunchKernelGGL(main_kernel, dim3(2304), dim3(256), 0, stream,
                       x, Wfrag, wgt, tws, perm, cnt, out);
}

// Round 19
// 164.267 us; speedup vs baseline: 3.8408x; 1.1288x over previous
//
#include <hip/hip_runtime.h>
#include <hip/hip_bf16.h>

typedef __attribute__((ext_vector_type(4))) float f32x4;
typedef __attribute__((ext_vector_type(8))) short s16x8;

#define NTOK 65536
// K layout (1056 = 33 chunks of 32): 16 pairs [32 Wb-k | 32 We-k], then tail
// chunk 32: [8 LoRA-B rows | bb | be | 22 zero].

__device__ __forceinline__ unsigned short f2b(float f) {
    __hip_bfloat16 h = __float2bfloat16(f);
    return *reinterpret_cast<unsigned short*>(&h);
}

// ---------------- P1: fused router (blocks 0..1023) + prep (1024..9471) -----
// Router: 256 thr, 4 waves x 16 tokens (setup amortized over 16 tokens),
// processed 2 per iteration -> interleaved reduce trees (2x ILP on the
// dependent shfl chains) + 2-token x prefetch distance.
__global__ __launch_bounds__(256) void prep_router_kernel(
    const float* __restrict__ x, const float* __restrict__ A,
    const float* __restrict__ Wr, const float* __restrict__ br,
    const float* __restrict__ Wb, const float* __restrict__ bb,
    const float* __restrict__ B, const float* __restrict__ ia3,
    const float* __restrict__ We, const float* __restrict__ be,
    unsigned short* __restrict__ Wfrag,
    float* __restrict__ wgt, float* __restrict__ tws,
    int* __restrict__ perm, int* __restrict__ cnt)
{
    const int tid = threadIdx.x;
    if (blockIdx.x >= 1024) {
        // ---------------- prep: Wfrag[e][c][cb][lane][8] MFMA-frag order ----
        int i = (blockIdx.x - 1024) * 256 + tid;    // 4*33*32*512 = 2162688
        if (i >= 4 * 33 * 32 * 512) return;
        const int j    = i & 7;
        const int lane = (i >> 3) & 63;
        const int cb   = (i >> 9) & 31;
        const int rest = i >> 14;                   // e*33 + c
        const int c    = rest % 33;
        const int e    = rest / 33;
        const int col  = cb * 16 + (lane & 15);
        const int klin = c * 32 + ((lane >> 4) << 3) + j;
        float v;
        if (klin < 1024) {
            const int p = klin >> 6, q = klin & 63;
            if (q < 32) v = Wb[col * 512 + p * 32 + q] * ia3[col];
            else        v = We[((size_t)e * 512 + col) * 512 + p * 32 + (q - 32)];
        }
        else if (klin < 1032)  v = B[(klin - 1024) * 512 + col] * 4.0f * ia3[col];
        else if (klin == 1032) v = bb[col] * ia3[col];
        else if (klin == 1033) v = be[e * 512 + col];
        else                   v = 0.0f;
        Wfrag[i] = f2b(v);
        return;
    }

    // ---------------- router: 4 waves x 16 tokens, 2 tokens/iter ----------
    __shared__ int sCnt[4];
    __shared__ int sBase[4];
    __shared__ int sE[64];
    __shared__ int sPos[64];

    const int wave = tid >> 6, lane = tid & 63;
    const int k0 = lane * 8;

    f32x4 wrv[4][2];
#pragma unroll
    for (int e = 0; e < 4; ++e) {
        wrv[e][0] = *(const f32x4*)(Wr + e * 512 + k0);
        wrv[e][1] = *(const f32x4*)(Wr + e * 512 + k0 + 4);
    }
    f32x4 av[8][2];
#pragma unroll
    for (int j = 0; j < 8; ++j) {
        av[j][0] = *(const f32x4*)(A + (size_t)(k0 + j) * 8);
        av[j][1] = *(const f32x4*)(A + (size_t)(k0 + j) * 8 + 4);
    }
    const float br0 = br[0], br1 = br[1], br2 = br[2], br3 = br[3];

    if (tid < 4) sCnt[tid] = 0;
    __syncthreads();

    const int tok0 = blockIdx.x * 64 + wave * 16;
    // current dual-token pair (A = even, B = odd) + next pair (prefetch)
    f32x4 xa0 = *(const f32x4*)(x + (size_t)tok0 * 512 + k0);
    f32x4 xa1 = *(const f32x4*)(x + (size_t)tok0 * 512 + k0 + 4);
    f32x4 xb0 = *(const f32x4*)(x + (size_t)(tok0 + 1) * 512 + k0);
    f32x4 xb1 = *(const f32x4*)(x + (size_t)(tok0 + 1) * 512 + k0 + 4);
#pragma unroll
    for (int jt = 0; jt < 8; ++jt) {
        const int tokA = tok0 + 2 * jt;
        f32x4 na0, na1, nb0, nb1;
        if (jt < 7) {
            const float* nrA = x + (size_t)(tokA + 2) * 512 + k0;
            const float* nrB = x + (size_t)(tokA + 3) * 512 + k0;
            na0 = *(const f32x4*)nrA;  na1 = *(const f32x4*)(nrA + 4);
            nb0 = *(const f32x4*)nrB;  nb1 = *(const f32x4*)(nrB + 4);
        }
        float arA[4] = {0.f, 0.f, 0.f, 0.f}, arB[4] = {0.f, 0.f, 0.f, 0.f};
        float atA[8] = {0.f, 0.f, 0.f, 0.f, 0.f, 0.f, 0.f, 0.f};
        float atB[8] = {0.f, 0.f, 0.f, 0.f, 0.f, 0.f, 0.f, 0.f};
#pragma unroll
        for (int j = 0; j < 8; ++j) {
            const float xvA = (j < 4) ? xa0[j] : xa1[j - 4];
            const float xvB = (j < 4) ? xb0[j] : xb1[j - 4];
#pragma unroll
            for (int e = 0; e < 4; ++e) {
                arA[e] += xvA * wrv[e][j >> 2][j & 3];
                arB[e] += xvB * wrv[e][j >> 2][j & 3];
            }
#pragma unroll
            for (int r = 0; r < 8; ++r) {
                atA[r] += xvA * av[j][r >> 2][r & 3];
                atB[r] += xvB * av[j][r >> 2][r & 3];
            }
        }
        // interleaved butterflies: two independent trees -> 2x chain ILP
#pragma unroll
        for (int off = 32; off >= 1; off >>= 1) {
#pragma unroll
            for (int e = 0; e < 4; ++e) {
                arA[e] += __shfl_xor(arA[e], off);
                arB[e] += __shfl_xor(arB[e], off);
            }
#pragma unroll
            for (int r = 0; r < 8; ++r) {
                atA[r] += __shfl_xor(atA[r], off);
                atB[r] += __shfl_xor(atB[r], off);
            }
        }
        if (lane == 0) {
            // token A
            {
                const float l0 = arA[0] + br0, l1 = arA[1] + br1;
                const float l2 = arA[2] + br2, l3 = arA[3] + br3;
                int e = 0; float m = l0;
                if (l1 > m) { m = l1; e = 1; }
                if (l2 > m) { m = l2; e = 2; }
                if (l3 > m) { m = l3; e = 3; }
                const float s = expf(l0 - m) + expf(l1 - m) + expf(l2 - m) + expf(l3 - m);
                wgt[tokA] = 1.0f / s;
                float* tp = tws + (size_t)tokA * 8;
#pragma unroll
                for (int r = 0; r < 8; ++r) tp[r] = atA[r];
                const int slot = wave * 16 + 2 * jt;
                sE[slot] = e;
                sPos[slot] = atomicAdd(&sCnt[e], 1);
            }
            // token B
            {
                const float l0 = arB[0] + br0, l1 = arB[1] + br1;
                const float l2 = arB[2] + br2, l3 = arB[3] + br3;
                int e = 0; float m = l0;
                if (l1 > m) { m = l1; e = 1; }
                if (l2 > m) { m = l2; e = 2; }
                if (l3 > m) { m = l3; e = 3; }
                const float s = expf(l0 - m) + expf(l1 - m) + expf(l2 - m) + expf(l3 - m);
                wgt[tokA + 1] = 1.0f / s;
                float* tp = tws + (size_t)(tokA + 1) * 8;
#pragma unroll
                for (int r = 0; r < 8; ++r) tp[r] = atB[r];
                const int slot = wave * 16 + 2 * jt + 1;
                sE[slot] = e;
                sPos[slot] = atomicAdd(&sCnt[e], 1);
            }
        }
        xa0 = na0; xa1 = na1; xb0 = nb0; xb1 = nb1;
    }
    __syncthreads();
    if (tid < 4) sBase[tid] = atomicAdd(&cnt[tid], sCnt[tid]);
    __syncthreads();
    if (tid < 64) {
        const int e = sE[tid];
        perm[e * NTOK + sBase[e] + sPos[tid]] = blockIdx.x * 64 + tid;
    }
}

// ---------------- P3: 64x256 tile, B global->reg (fragment-coalesced) -------
// Proven optimum (R13/R15/R18): 4 waves, wave-tile 64x64, B triple-buffered
// in regs via Wfrag coalesced dwordx4, zero B-path barriers; A: 4 x 8 KB LDS
// ring staged two pairs ahead, barrier every other pair. launch_bounds(256,3)
// = 84 VGPR, NO SPILL (min-waves=4 forces 64-reg cap -> scratch, R17).
__global__ __launch_bounds__(256, 3) void main_kernel(
    const float* __restrict__ x, const unsigned short* __restrict__ Wfrag,
    const float* __restrict__ wgt, const float* __restrict__ tws,
    const int* __restrict__ perm, const int* __restrict__ cnt,
    float* __restrict__ out)
{
    __shared__ unsigned short sA[4][64 * 64];    // 4 x 8 KB ring, pair p -> p&3

    const int bid = blockIdx.x;
    const int xcd = bid & 7;
    const int e = xcd >> 1;
    const int par = xcd & 1;
    const int r = bid >> 3;
    const int half = r & 1;
    const int mt = (r >> 1) * 2 + par;
    const int n = cnt[e];
    const int base = mt * 64;
    if (base >= n) return;
    const int mcount = min(64, n - base);

    const int tid = threadIdx.x;
    const int lane = tid & 63;
    const int wave = tid >> 6;      // 0..3: owns cols half*256 + wave*64 ..+63
    const int lanelo = lane & 15;
    const int g = lane >> 4;        // 0..3

    // ---- A staging: thread -> (arow = tid>>2, s = tid&3); 8 f32 per pair ---
    const int arow = tid >> 2;
    const int s = tid & 3;
    const int atok = perm[e * NTOK + base + min(arow, mcount - 1)];
    const float* axp = x + (size_t)atok * 512 + s * 8;
    const float* atp = tws + (size_t)atok * 8;
    const float aw = wgt[atok];
    const int arx = arow & 7;
    const int adP = arow * 128 + ((s ^ arx) << 4);        // plain granule
    const int adS = arow * 128 + (((4 + s) ^ arx) << 4);  // w-scaled granule

    // ---- B: 4 fragment base pointers, each loads at +lane*16 (coalesced) ---
    const unsigned short* wB[4];
#pragma unroll
    for (int nb = 0; nb < 4; ++nb) {
        const int cb = half * 16 + wave * 4 + nb;          // colblk 0..31
        wB[nb] = Wfrag + (((size_t)e * 33 * 32) + cb) * 512 + lane * 8;
    }

    // triple-buffered B fragments; all indices compile-time after full unroll
    s16x8 bB[3][4];
    auto loadB = [&](int c, int ring) {
        const size_t co = (size_t)c * 32 * 512;            // chunk stride (elems)
#pragma unroll
        for (int nb = 0; nb < 4; ++nb)
            bB[ring][nb] = *(const s16x8*)(wB[nb] + co);
    };

    f32x4 qa, qb;   // A staging regs (named)
    auto loadA = [&](int p) {
        if (p < 16) {
            qa = *(const f32x4*)(axp + p * 32);
            qb = *(const f32x4*)(axp + p * 32 + 4);
        } else {
            qa = *(const f32x4*)atp;
            qb = *(const f32x4*)(atp + 4);
        }
    };
    auto writeA = [&](int p) {
        char* aB = (char*)sA[p & 3];
        s16x8 h0, h1;
        if (p < 16) {
#pragma unroll
            for (int j4 = 0; j4 < 4; ++j4) {
                h0[j4]     = (short)f2b(qa[j4]);
                h0[j4 + 4] = (short)f2b(qb[j4]);
                h1[j4]     = (short)f2b(aw * qa[j4]);
                h1[j4 + 4] = (short)f2b(aw * qb[j4]);
            }
        } else {
#pragma unroll
            for (int j4 = 0; j4 < 8; ++j4) { h0[j4] = 0; h1[j4] = 0; }
            if (s == 0) {
#pragma unroll
                for (int j4 = 0; j4 < 4; ++j4) {
                    h0[j4]     = (short)f2b(qa[j4]);
                    h0[j4 + 4] = (short)f2b(qb[j4]);
                }
            } else if (s == 1) {
                h0[0] = (short)f2b(1.0f);
                h0[1] = (short)f2b(aw);
            }
        }
        *(s16x8*)(aB + adP) = h0;
        *(s16x8*)(aB + adS) = h1;
    };

    f32x4 acc[4][4];
#pragma unroll
    for (int mb = 0; mb < 4; ++mb)
#pragma unroll
        for (int nb = 0; nb < 4; ++nb) acc[mb][nb] = (f32x4){0.f, 0.f, 0.f, 0.f};

    auto computeC = [&](int h, int abuf, int ring) {
        const char* bA = (const char*)sA[abuf];
        s16x8 a[4];
#pragma unroll
        for (int mb = 0; mb < 4; ++mb) {
            const int row = mb * 16 + lanelo;
            a[mb] = *(const s16x8*)(bA + row * 128 + ((((h << 2) + g) ^ (row & 7)) << 4));
        }
        __builtin_amdgcn_s_setprio(1);
#pragma unroll
        for (int mb = 0; mb < 4; ++mb)
#pragma unroll
            for (int nb = 0; nb < 4; ++nb)
                acc[mb][nb] = __builtin_amdgcn_mfma_f32_16x16x32_bf16(a[mb], bB[ring][nb], acc[mb][nb], 0, 0, 0);
        __builtin_amdgcn_s_setprio(0);
    };

    // ---- prologue: A before B in FIFO; B(0..2) in flight (chunk c -> c%3) --
    loadA(0);
    loadB(0, 0);
    loadB(1, 1);
    loadB(2, 2);
    writeA(0);                    // compiler vmcnt retires only the A load
    loadA(1);
    writeA(1);
    asm volatile("s_waitcnt lgkmcnt(0)" ::: "memory");
    __builtin_amdgcn_sched_barrier(0);
    __builtin_amdgcn_s_barrier();
    __builtin_amdgcn_sched_barrier(0);

    // pair p lives in sA[p&3]; written 2 iters ahead; barrier after odd iters.
    // chunk c lives in bB[c%3]; refilled with chunk c+3 right after use.
#pragma unroll
    for (int j = 0; j < 16; ++j) {
        if (j < 15) loadA(j + 2);          // prefetch pair j+2 (global)
        computeC(0, j & 3, (2 * j) % 3);   // chunk 2j (auto-wait on its regs)
        if (2 * j + 3 <= 32) loadB(2 * j + 3, (2 * j) % 3);
        computeC(1, j & 3, (2 * j + 1) % 3);
        if (2 * j + 4 <= 32) loadB(2 * j + 4, (2 * j + 1) % 3);
        if (j < 15) writeA(j + 2);         // ring slot (j+2)&3: race-free
        if (j & 1) {
            asm volatile("s_waitcnt lgkmcnt(0)" ::: "memory");
            __builtin_amdgcn_sched_barrier(0);
            __builtin_amdgcn_s_barrier();  // one barrier per TWO pairs
            __builtin_amdgcn_sched_barrier(0);
        }
    }

    // ---- tail pair 16 (chunk 32: LoRA + biases + w); 32%3 == 2 ----
    computeC(0, 0, 2);

    // ---- epilogue: bare scattered store ----
    const int col0 = half * 256 + wave * 64 + lanelo;
#pragma unroll
    for (int mb = 0; mb < 4; ++mb) {
#pragma unroll
        for (int rr = 0; rr < 4; ++rr) {
            const int trow = mb * 16 + g * 4 + rr;
            if (trow < mcount) {
                const int tok = perm[e * NTOK + base + trow];
                float* orow = out + (size_t)tok * 512 + col0;
                orow[0]  = acc[mb][0][rr];
                orow[16] = acc[mb][1][rr];
                orow[32] = acc[mb][2][rr];
                orow[48] = acc[mb][3][rr];
            }
        }
    }
}

extern "C" void kernel_launch(void* const* d_in, const int* in_sizes, int n_in,
                              void* d_out, int out_size, void* d_ws, size_t ws_size,
                              hipStream_t stream)
{
    const float* x   = (const float*)d_in[0];
    const float* Wb  = (const float*)d_in[1];
    const float* bb  = (const float*)d_in[2];
    const float* A   = (const float*)d_in[3];
    const float* B   = (const float*)d_in[4];
    const float* ia3 = (const float*)d_in[5];
    const float* Wr  = (const float*)d_in[6];
    const float* br  = (const float*)d_in[7];
    const float* We  = (const float*)d_in[8];
    const float* be  = (const float*)d_in[9];
    float* out = (float*)d_out;

    char* w = (char*)d_ws;
    int* cnt              = (int*)w;                      // 256 B
    unsigned short* Wfrag = (unsigned short*)(w + 256);   // 4*33*32*512*2 = 4325376
    float* wgt            = (float*)(w + 4325632);        // 65536*4
    float* tws            = (float*)(w + 4587776);        // 65536*8*4
    int* perm             = (int*)(w + 6684928);          // 4*65536*4 -> end 7733504

    hipMemsetAsync(cnt, 0, 16, stream);   // zero expert counters (graph-legal)
    // blocks 0..1023 = router (4 waves x 16 tokens); 1024..9471 = prep (256)
    hipLaunchKernelGGL(prep_router_kernel, dim3(9472), dim3(256), 0, stream,
                       x, A, Wr, br, Wb, bb, B, ia3, We, be,
                       Wfrag, wgt, tws, perm, cnt);
    // 8 xcd x 144 slots x 2 halves
    hipLaunchKernelGGL(main_kernel, dim3(2304), dim3(256), 0, stream,
                       x, Wfrag, wgt, tws, perm, cnt, out);
}

// Round 20
// 123.816 us; speedup vs baseline: 5.0956x; 1.3267x over previous
//
#include <hip/hip_runtime.h>
#include <hip/hip_bf16.h>

typedef __attribute__((ext_vector_type(4))) float f32x4;
typedef __attribute__((ext_vector_type(8))) short s16x8;

#define NTOK 65536
// K layout (1056 = 33 chunks of 32): 16 pairs [32 Wb_eff-k | 32 We-k], tail
// chunk 32: [bb | be | 30 zero]. LoRA is FOLDED into Wb_eff = ia3*(Wb + 4*A@B^T).

__device__ __forceinline__ unsigned short f2b(float f) {
    __hip_bfloat16 h = __float2bfloat16(f);
    return *reinterpret_cast<unsigned short*>(&h);
}

// ---------------- P1: fused router (blocks 0..1023) + prep (1024..9471) -----
// Router: 256 thr, 4 waves x 16 tokens, 2 tokens/iter; ONLY the 4 router
// logits remain (LoRA folded into weights) -> 32 FMA + 24 ds-ops per token.
__global__ __launch_bounds__(256) void prep_router_kernel(
    const float* __restrict__ x, const float* __restrict__ A,
    const float* __restrict__ Wr, const float* __restrict__ br,
    const float* __restrict__ Wb, const float* __restrict__ bb,
    const float* __restrict__ B, const float* __restrict__ ia3,
    const float* __restrict__ We, const float* __restrict__ be,
    unsigned short* __restrict__ Wfrag,
    float* __restrict__ wgt,
    int* __restrict__ perm, int* __restrict__ cnt)
{
    const int tid = threadIdx.x;
    if (blockIdx.x >= 1024) {
        // ---------------- prep: Wfrag[e][c][cb][lane][8] MFMA-frag order ----
        int i = (blockIdx.x - 1024) * 256 + tid;    // 4*33*32*512 = 2162688
        if (i >= 4 * 33 * 32 * 512) return;
        const int j    = i & 7;
        const int lane = (i >> 3) & 63;
        const int cb   = (i >> 9) & 31;
        const int rest = i >> 14;                   // e*33 + c
        const int c    = rest % 33;
        const int e    = rest / 33;
        const int col  = cb * 16 + (lane & 15);
        const int klin = c * 32 + ((lane >> 4) << 3) + j;
        float v;
        if (klin < 1024) {
            const int p = klin >> 6, q = klin & 63;
            if (q < 32) {
                const int k = p * 32 + q;           // Wb_eff input index
                float lora = 0.f;
                const float* Ar = A + (size_t)k * 8;
#pragma unroll
                for (int r8 = 0; r8 < 8; ++r8) lora += Ar[r8] * B[r8 * 512 + col];
                v = (Wb[col * 512 + k] + 4.0f * lora) * ia3[col];
            } else {
                v = We[((size_t)e * 512 + col) * 512 + p * 32 + (q - 32)];
            }
        }
        else if (klin == 1024) v = bb[col] * ia3[col];
        else if (klin == 1025) v = be[e * 512 + col];
        else                   v = 0.0f;
        Wfrag[i] = f2b(v);
        return;
    }

    // ---------------- router: 4 waves x 16 tokens, 2 tokens/iter ----------
    __shared__ int sCnt[4];
    __shared__ int sBase[4];
    __shared__ int sE[64];
    __shared__ int sPos[64];

    const int wave = tid >> 6, lane = tid & 63;
    const int k0 = lane * 8;

    f32x4 wrv[4][2];
#pragma unroll
    for (int e = 0; e < 4; ++e) {
        wrv[e][0] = *(const f32x4*)(Wr + e * 512 + k0);
        wrv[e][1] = *(const f32x4*)(Wr + e * 512 + k0 + 4);
    }
    const float br0 = br[0], br1 = br[1], br2 = br[2], br3 = br[3];

    if (tid < 4) sCnt[tid] = 0;
    __syncthreads();

    const int tok0 = blockIdx.x * 64 + wave * 16;
    f32x4 xa0 = *(const f32x4*)(x + (size_t)tok0 * 512 + k0);
    f32x4 xa1 = *(const f32x4*)(x + (size_t)tok0 * 512 + k0 + 4);
    f32x4 xb0 = *(const f32x4*)(x + (size_t)(tok0 + 1) * 512 + k0);
    f32x4 xb1 = *(const f32x4*)(x + (size_t)(tok0 + 1) * 512 + k0 + 4);
#pragma unroll
    for (int jt = 0; jt < 8; ++jt) {
        const int tokA = tok0 + 2 * jt;
        f32x4 na0, na1, nb0, nb1;
        if (jt < 7) {
            const float* nrA = x + (size_t)(tokA + 2) * 512 + k0;
            const float* nrB = x + (size_t)(tokA + 3) * 512 + k0;
            na0 = *(const f32x4*)nrA;  na1 = *(const f32x4*)(nrA + 4);
            nb0 = *(const f32x4*)nrB;  nb1 = *(const f32x4*)(nrB + 4);
        }
        float arA[4] = {0.f, 0.f, 0.f, 0.f}, arB[4] = {0.f, 0.f, 0.f, 0.f};
#pragma unroll
        for (int j = 0; j < 8; ++j) {
            const float xvA = (j < 4) ? xa0[j] : xa1[j - 4];
            const float xvB = (j < 4) ? xb0[j] : xb1[j - 4];
#pragma unroll
            for (int e = 0; e < 4; ++e) {
                arA[e] += xvA * wrv[e][j >> 2][j & 3];
                arB[e] += xvB * wrv[e][j >> 2][j & 3];
            }
        }
#pragma unroll
        for (int off = 32; off >= 1; off >>= 1) {
#pragma unroll
            for (int e = 0; e < 4; ++e) {
                arA[e] += __shfl_xor(arA[e], off);
                arB[e] += __shfl_xor(arB[e], off);
            }
        }
        if (lane == 0) {
            {
                const float l0 = arA[0] + br0, l1 = arA[1] + br1;
                const float l2 = arA[2] + br2, l3 = arA[3] + br3;
                int e = 0; float m = l0;
                if (l1 > m) { m = l1; e = 1; }
                if (l2 > m) { m = l2; e = 2; }
                if (l3 > m) { m = l3; e = 3; }
                const float s = expf(l0 - m) + expf(l1 - m) + expf(l2 - m) + expf(l3 - m);
                wgt[tokA] = 1.0f / s;
                const int slot = wave * 16 + 2 * jt;
                sE[slot] = e;
                sPos[slot] = atomicAdd(&sCnt[e], 1);
            }
            {
                const float l0 = arB[0] + br0, l1 = arB[1] + br1;
                const float l2 = arB[2] + br2, l3 = arB[3] + br3;
                int e = 0; float m = l0;
                if (l1 > m) { m = l1; e = 1; }
                if (l2 > m) { m = l2; e = 2; }
                if (l3 > m) { m = l3; e = 3; }
                const float s = expf(l0 - m) + expf(l1 - m) + expf(l2 - m) + expf(l3 - m);
                wgt[tokA + 1] = 1.0f / s;
                const int slot = wave * 16 + 2 * jt + 1;
                sE[slot] = e;
                sPos[slot] = atomicAdd(&sCnt[e], 1);
            }
        }
        xa0 = na0; xa1 = na1; xb0 = nb0; xb1 = nb1;
    }
    __syncthreads();
    if (tid < 4) sBase[tid] = atomicAdd(&cnt[tid], sCnt[tid]);
    __syncthreads();
    if (tid < 64) {
        const int e = sE[tid];
        perm[e * NTOK + sBase[e] + sPos[tid]] = blockIdx.x * 64 + tid;
    }
}

// ---------------- P3: 64x256 tile, B global->reg (fragment-coalesced) -------
// Proven optimum (R13/R15/R19): 4 waves, wave-tile 64x64, B triple-buffered
// in regs via Wfrag coalesced dwordx4, zero B-path barriers; A: 4 x 8 KB LDS
// ring staged two pairs ahead, barrier every other pair. launch_bounds(256,3)
// = 84 VGPR, NO SPILL (min-waves=4 forces 64-reg cap -> scratch, R17).
// Tail chunk is now just [1->bb, w->be] constants (LoRA folded into Wb_eff).
__global__ __launch_bounds__(256, 3) void main_kernel(
    const float* __restrict__ x, const unsigned short* __restrict__ Wfrag,
    const float* __restrict__ wgt,
    const int* __restrict__ perm, const int* __restrict__ cnt,
    float* __restrict__ out)
{
    __shared__ unsigned short sA[4][64 * 64];    // 4 x 8 KB ring, pair p -> p&3

    const int bid = blockIdx.x;
    const int xcd = bid & 7;
    const int e = xcd >> 1;
    const int par = xcd & 1;
    const int r = bid >> 3;
    const int half = r & 1;
    const int mt = (r >> 1) * 2 + par;
    const int n = cnt[e];
    const int base = mt * 64;
    if (base >= n) return;
    const int mcount = min(64, n - base);

    const int tid = threadIdx.x;
    const int lane = tid & 63;
    const int wave = tid >> 6;      // 0..3: owns cols half*256 + wave*64 ..+63
    const int lanelo = lane & 15;
    const int g = lane >> 4;        // 0..3

    // ---- A staging: thread -> (arow = tid>>2, s = tid&3); 8 f32 per pair ---
    const int arow = tid >> 2;
    const int s = tid & 3;
    const int atok = perm[e * NTOK + base + min(arow, mcount - 1)];
    const float* axp = x + (size_t)atok * 512 + s * 8;
    const float aw = wgt[atok];
    const int arx = arow & 7;
    const int adP = arow * 128 + ((s ^ arx) << 4);        // plain granule
    const int adS = arow * 128 + (((4 + s) ^ arx) << 4);  // w-scaled granule

    // ---- B: 4 fragment base pointers, each loads at +lane*16 (coalesced) ---
    const unsigned short* wB[4];
#pragma unroll
    for (int nb = 0; nb < 4; ++nb) {
        const int cb = half * 16 + wave * 4 + nb;          // colblk 0..31
        wB[nb] = Wfrag + (((size_t)e * 33 * 32) + cb) * 512 + lane * 8;
    }

    // triple-buffered B fragments; all indices compile-time after full unroll
    s16x8 bB[3][4];
    auto loadB = [&](int c, int ring) {
        const size_t co = (size_t)c * 32 * 512;            // chunk stride (elems)
#pragma unroll
        for (int nb = 0; nb < 4; ++nb)
            bB[ring][nb] = *(const s16x8*)(wB[nb] + co);
    };

    f32x4 qa, qb;   // A staging regs (named)
    auto loadA = [&](int p) {
        if (p < 16) {
            qa = *(const f32x4*)(axp + p * 32);
            qb = *(const f32x4*)(axp + p * 32 + 4);
        }
    };
    auto writeA = [&](int p) {
        char* aB = (char*)sA[p & 3];
        s16x8 h0, h1;
        if (p < 16) {
#pragma unroll
            for (int j4 = 0; j4 < 4; ++j4) {
                h0[j4]     = (short)f2b(qa[j4]);
                h0[j4 + 4] = (short)f2b(qb[j4]);
                h1[j4]     = (short)f2b(aw * qa[j4]);
                h1[j4 + 4] = (short)f2b(aw * qb[j4]);
            }
        } else {
            // tail pair: granule 0 = [1 -> bb, w -> be, 0...]; rest zero
#pragma unroll
            for (int j4 = 0; j4 < 8; ++j4) { h0[j4] = 0; h1[j4] = 0; }
            if (s == 0) {
                h0[0] = (short)f2b(1.0f);
                h0[1] = (short)f2b(aw);
            }
        }
        *(s16x8*)(aB + adP) = h0;
        *(s16x8*)(aB + adS) = h1;
    };

    f32x4 acc[4][4];
#pragma unroll
    for (int mb = 0; mb < 4; ++mb)
#pragma unroll
        for (int nb = 0; nb < 4; ++nb) acc[mb][nb] = (f32x4){0.f, 0.f, 0.f, 0.f};

    auto computeC = [&](int h, int abuf, int ring) {
        const char* bA = (const char*)sA[abuf];
        s16x8 a[4];
#pragma unroll
        for (int mb = 0; mb < 4; ++mb) {
            const int row = mb * 16 + lanelo;
            a[mb] = *(const s16x8*)(bA + row * 128 + ((((h << 2) + g) ^ (row & 7)) << 4));
        }
        __builtin_amdgcn_s_setprio(1);
#pragma unroll
        for (int mb = 0; mb < 4; ++mb)
#pragma unroll
            for (int nb = 0; nb < 4; ++nb)
                acc[mb][nb] = __builtin_amdgcn_mfma_f32_16x16x32_bf16(a[mb], bB[ring][nb], acc[mb][nb], 0, 0, 0);
        __builtin_amdgcn_s_setprio(0);
    };

    // ---- prologue: A before B in FIFO; B(0..2) in flight (chunk c -> c%3) --
    loadA(0);
    loadB(0, 0);
    loadB(1, 1);
    loadB(2, 2);
    writeA(0);                    // compiler vmcnt retires only the A load
    loadA(1);
    writeA(1);
    asm volatile("s_waitcnt lgkmcnt(0)" ::: "memory");
    __builtin_amdgcn_sched_barrier(0);
    __builtin_amdgcn_s_barrier();
    __builtin_amdgcn_sched_barrier(0);

    // pair p lives in sA[p&3]; written 2 iters ahead; barrier after odd iters.
    // chunk c lives in bB[c%3]; refilled with chunk c+3 right after use.
#pragma unroll
    for (int j = 0; j < 16; ++j) {
        if (j < 15) loadA(j + 2);          // prefetch pair j+2 (global)
        computeC(0, j & 3, (2 * j) % 3);   // chunk 2j (auto-wait on its regs)
        if (2 * j + 3 <= 32) loadB(2 * j + 3, (2 * j) % 3);
        computeC(1, j & 3, (2 * j + 1) % 3);
        if (2 * j + 4 <= 32) loadB(2 * j + 4, (2 * j + 1) % 3);
        if (j < 15) writeA(j + 2);         // ring slot (j+2)&3: race-free
        if (j & 1) {
            asm volatile("s_waitcnt lgkmcnt(0)" ::: "memory");
            __builtin_amdgcn_sched_barrier(0);
            __builtin_amdgcn_s_barrier();  // one barrier per TWO pairs
            __builtin_amdgcn_sched_barrier(0);
        }
    }

    // ---- tail pair 16 (chunk 32: biases + w); 32%3 == 2 ----
    computeC(0, 0, 2);

    // ---- epilogue: bare scattered store ----
    const int col0 = half * 256 + wave * 64 + lanelo;
#pragma unroll
    for (int mb = 0; mb < 4; ++mb) {
#pragma unroll
        for (int rr = 0; rr < 4; ++rr) {
            const int trow = mb * 16 + g * 4 + rr;
            if (trow < mcount) {
                const int tok = perm[e * NTOK + base + trow];
                float* orow = out + (size_t)tok * 512 + col0;
                orow[0]  = acc[mb][0][rr];
                orow[16] = acc[mb][1][rr];
                orow[32] = acc[mb][2][rr];
                orow[48] = acc[mb][3][rr];
            }
        }
    }
}

extern "C" void kernel_launch(void* const* d_in, const int* in_sizes, int n_in,
                              void* d_out, int out_size, void* d_ws, size_t ws_size,
                              hipStream_t stream)
{
    const float* x   = (const float*)d_in[0];
    const float* Wb  = (const float*)d_in[1];
    const float* bb  = (const float*)d_in[2];
    const float* A   = (const float*)d_in[3];
    const float* B   = (const float*)d_in[4];
    const float* ia3 = (const float*)d_in[5];
    const float* Wr  = (const float*)d_in[6];
    const float* br  = (const float*)d_in[7];
    const float* We  = (const float*)d_in[8];
    const float* be  = (const float*)d_in[9];
    float* out = (float*)d_out;

    char* w = (char*)d_ws;
    int* cnt              = (int*)w;                      // 256 B
    unsigned short* Wfrag = (unsigned short*)(w + 256);   // 4*33*32*512*2 = 4325376
    float* wgt            = (float*)(w + 4325632);        // 65536*4
    int* perm             = (int*)(w + 4587776);          // 4*65536*4 -> end 5636352

    hipMemsetAsync(cnt, 0, 16, stream);   // zero expert counters (graph-legal)
    // blocks 0..1023 = router; 1024..9471 = prep (256 thr)
    hipLaunchKernelGGL(prep_router_kernel, dim3(9472), dim3(256), 0, stream,
                       x, A, Wr, br, Wb, bb, B, ia3, We, be,
                       Wfrag, wgt, perm, cnt);
    // 8 xcd x 144 slots x 2 halves
    hipLaunchKernelGGL(main_kernel, dim3(2304), dim3(256), 0, stream,
                       x, Wfrag, wgt, perm, cnt, out);
}